// Round 2
// 739.481 us; speedup vs baseline: 1.1159x; 1.1159x over previous
//
#include <hip/hip_runtime.h>
#include <math.h>

typedef unsigned short ushort_t;
typedef __attribute__((ext_vector_type(8))) short short8;
typedef __attribute__((ext_vector_type(4))) float floatx4;
typedef __attribute__((ext_vector_type(8))) unsigned short ushortx8;

#define NROW 49408   // B*L = 256*193
#define MT   772     // NROW/64

__device__ __forceinline__ float b2f(ushort_t u){
  union { float f; unsigned int i; } v; v.i = ((unsigned int)u) << 16; return v.f;
}
__device__ __forceinline__ ushort_t f2b(float f){
  unsigned int i = __float_as_uint(f);
  unsigned int r = (i + 0x7FFFu + ((i >> 16) & 1u)) >> 16;
  return (ushort_t)r;
}

struct Args {
  const float *state,*C0,*C1,*C2,*C3,*C4,*C5;
  const float *Wq,*Wk,*Wv,*bq,*bk,*bv;
  const float *WCq,*WCk,*WCv,*bCq,*bCk,*bCv;
  const float *gQE,*beQE,*gKE,*beKE,*gVE,*beVE;
  const float *gQH,*beQH,*gKH,*beKH,*gVH,*beVH;
  const float *g1,*be1,*W1,*bl1,*W2,*bl2;
  float *qws,*kws,*vws;           // fp32 [B*H, 193, 32]
  ushort_t *attws,*z2ws;          // bf16 [NROW,64]
  ushort_t *weT,*whT,*w1T,*w2T;   // bf16 pre-transposed weights
  float *out;                     // fp32 [NROW,64]  <-- output IS float32
};

// ------------- weight convert+transpose ---------------------------------
// Layout for weT/whT: K-panel-contiguous [kc][192 n][32 kk] so k_proj
// waves can load B fragments directly global->reg fully coalesced.
__global__ __launch_bounds__(256) void k_prep(Args A){
  int i = blockIdx.x*256 + threadIdx.x;
  int stride = gridDim.x*256;
  const float* We[3] = {A.Wq, A.Wk, A.Wv};
  const float* Wh[3] = {A.WCq, A.WCk, A.WCv};
  // weT: 2 panels of [192][32];  element (k=kc*32+kk, n)
  for (int p=i; p<2*6144; p+=stride){
    int kc = p / 6144, r = p - kc*6144, n = r >> 5, kk = r & 31;
    A.weT[p] = f2b(We[n>>6][(kc*32+kk)*64 + (n&63)]);
  }
  // whT: 48 panels of [192][32]
  for (int p=i; p<48*6144; p+=stride){
    int kc = p / 6144, r = p - kc*6144, n = r >> 5, kk = r & 31;
    A.whT[p] = f2b(Wh[n>>6][(kc*32+kk)*64 + (n&63)]);
  }
  for (int p=i; p<256*64; p+=stride){ int n=p>>6, k=p&63; A.w1T[p] = f2b(A.W1[k*256 + n]); }   // w1T[256][64]
  for (int p=i; p<64*256; p+=stride){ int n=p>>8, k=p&255; A.w2T[p] = f2b(A.W2[k*64 + n]); }   // w2T[64][256]
}

// ------------- projections + LN-gate -> q/k/v ws (fp32, [B,H,L,32]) ---------
// B direct global->reg (L2-resident, no LDS staging),
// A double-buffered in LDS with 1-barrier/step reg-staged prefetch pipeline,
// LN epilogue buffers unioned with the A buffers (LDS 53.8KB -> 33.3KB).
#define LDA 40   // padded lds stride (32+8 ushorts) - conflict-free b128 reads
__global__ __launch_bounds__(256,3) void k_proj(Args A){
  const int mb = blockIdx.x;
  const int t  = threadIdx.x;
  const int w  = t >> 6;
  const int l  = t & 63;
  const int lr = l & 15;
  const int lq = l >> 4;
  const int arow = t >> 2, aseg = t & 3;

  struct __align__(16) SM {
    union {
      ushort_t Abuf[2][64*LDA];                      // 10240 B (double-buffered A tile)
      struct { float E[64][65]; float Hh[64][65]; } ln; // 33280 B (epilogue only)
    };
  };
  __shared__ SM sm;

  floatx4 accH[3][4];
  floatx4 accE[3][4];
  #pragma unroll
  for (int jj=0;jj<3;jj++)
    #pragma unroll
    for (int ra=0;ra<4;ra++){ accH[jj][ra] = floatx4{0.f,0.f,0.f,0.f}; accE[jj][ra] = floatx4{0.f,0.f,0.f,0.f}; }

  // uniform-select source pointer for A-tile of K-step k (avoids scratch array)
  auto loadA = [&](int k, float4& f0, float4& f1){
    const float* src;
    if (k < 48){
      int k0 = k*32;
      int sel = k0 >> 8;                 // 0..5, wave-uniform
      const float* cb = A.C0;
      if (sel==1) cb=A.C1; else if (sel==2) cb=A.C2; else if (sel==3) cb=A.C3;
      else if (sel==4) cb=A.C4; else if (sel==5) cb=A.C5;
      src = cb + (size_t)(mb*64 + arow)*256 + (k0 & 255) + aseg*8;
    } else {
      int k0 = (k-48)*32;
      src = A.state + (size_t)(mb*64 + arow)*64 + k0 + aseg*8;
    }
    f0 = *(const float4*)(src);
    f1 = *(const float4*)(src + 4);
  };
  auto storeA = [&](int buf, const float4& f0, const float4& f1){
    ushortx8 u;
    u[0]=f2b(f0.x); u[1]=f2b(f0.y); u[2]=f2b(f0.z); u[3]=f2b(f0.w);
    u[4]=f2b(f1.x); u[5]=f2b(f1.y); u[6]=f2b(f1.z); u[7]=f2b(f1.w);
    *(ushortx8*)(sm.Abuf[buf] + arow*LDA + aseg*8) = u;
  };

  // prologue: stage K-step 0
  {
    float4 c0, c1;
    loadA(0, c0, c1);
    storeA(0, c0, c1);
  }
  __syncthreads();

  // unified pipelined K loop: steps 0..47 = H branch (K=1536), 48..49 = E (K=64)
  for (int kc = 0; kc < 50; ++kc){
    const int cur = kc & 1;
    const bool more = (kc + 1) < 50;
    float4 n0, n1;
    if (more) loadA(kc+1, n0, n1);       // issue next A-tile loads (in flight across MFMA)

    // B fragments: direct global->reg. Panel-contiguous layout; per wave-load
    // the 16 rows x 64B are one contiguous 1KB block (fully coalesced, L2-hit).
    const ushort_t* bp = (kc < 48) ? (A.whT + (size_t)kc*6144)
                                   : (A.weT + (size_t)(kc-48)*6144);
    short8 b[3];
    #pragma unroll
    for (int jj=0;jj<3;jj++)
      b[jj] = *(const short8*)(bp + (48*w + 16*jj + lr)*32 + lq*8);

    short8 a[4];
    #pragma unroll
    for (int ra=0;ra<4;ra++)
      a[ra] = *(const short8*)(sm.Abuf[cur] + (16*ra + lr)*LDA + lq*8);

    if (kc < 48){
      #pragma unroll
      for (int jj=0;jj<3;jj++)
        #pragma unroll
        for (int ra=0;ra<4;ra++)
          accH[jj][ra] = __builtin_amdgcn_mfma_f32_16x16x32_bf16(a[ra], b[jj], accH[jj][ra], 0,0,0);
    } else {
      #pragma unroll
      for (int jj=0;jj<3;jj++)
        #pragma unroll
        for (int ra=0;ra<4;ra++)
          accE[jj][ra] = __builtin_amdgcn_mfma_f32_16x16x32_bf16(a[ra], b[jj], accE[jj][ra], 0,0,0);
    }

    if (more) storeA(cur^1, n0, n1);     // waits on the prefetch loads; buf cur^1 free since end of kc-1
    __syncthreads();                      // one barrier per K-step
  }

  // ---- epilogue: per group g in {q,k,v}: bias, LN(E)*LN(H), store ----
  const float* bEs[3]  = {A.bq,  A.bk,  A.bv};
  const float* bHs[3]  = {A.bCq, A.bCk, A.bCv};
  const float* gEs[3]  = {A.gQE, A.gKE, A.gVE};
  const float* beEs[3] = {A.beQE,A.beKE,A.beVE};
  const float* gHs[3]  = {A.gQH, A.gKH, A.gVH};
  const float* beHs[3] = {A.beQH,A.beKH,A.beVH};
  float* outw[3] = {A.qws, A.kws, A.vws};

  for (int g=0; g<3; ++g){
    #pragma unroll
    for (int jj=0;jj<3;jj++){
      int jg = 3*w + jj;                    // global 16-col tile 0..11
      if ((jg >> 2) == g){
        int colL = (jg & 3)*16 + lr;        // col within group, 0..63
        float be_ = bEs[g][colL];
        float bh_ = bHs[g][colL];
        #pragma unroll
        for (int ra=0;ra<4;ra++)
          #pragma unroll
          for (int r=0;r<4;r++){
            int row = 16*ra + lq*4 + r;
            sm.ln.E[row][colL]  = accE[jj][ra][r] + be_;
            sm.ln.Hh[row][colL] = accH[jj][ra][r] + bh_;
          }
      }
    }
    __syncthreads();
    {
      int r = t >> 2, q4 = t & 3;
      float sE=0.f, ssE=0.f, sH=0.f, ssH=0.f;
      #pragma unroll
      for (int c=0;c<16;c++){
        float e = sm.ln.E[r][q4*16+c];  sE += e; ssE += e*e;
        float h = sm.ln.Hh[r][q4*16+c]; sH += h; ssH += h*h;
      }
      sE  += __shfl_xor(sE,1);  sE  += __shfl_xor(sE,2);
      ssE += __shfl_xor(ssE,1); ssE += __shfl_xor(ssE,2);
      sH  += __shfl_xor(sH,1);  sH  += __shfl_xor(sH,2);
      ssH += __shfl_xor(ssH,1); ssH += __shfl_xor(ssH,2);
      float mE = sE*(1.f/64.f), vE = fmaxf(ssE*(1.f/64.f) - mE*mE, 0.f);
      float mH = sH*(1.f/64.f), vH = fmaxf(ssH*(1.f/64.f) - mH*mH, 0.f);
      float rE = rsqrtf(vE + 1e-5f), rH = rsqrtf(vH + 1e-5f);
      int G  = mb*64 + r;
      int bb = G / 193, lp = G - bb*193;
      float* ow = outw[g];
      #pragma unroll
      for (int c=0;c<16;c++){
        int cc = q4*16 + c;
        float e = (sm.ln.E[r][cc]-mE)*rE*gEs[g][cc] + beEs[g][cc];
        float h = (sm.ln.Hh[r][cc]-mH)*rH*gHs[g][cc] + beHs[g][cc];
        int hd = cc >> 5, d = cc & 31;
        ow[((size_t)(bb*2+hd)*193 + lp)*32 + d] = e*h;
      }
    }
    __syncthreads();
  }
}

// ------------- attention: one block per (b,h), query-per-thread -------------
__global__ __launch_bounds__(256) void k_attn(Args A){
  const int b = blockIdx.x, h = blockIdx.y;
  const int t = threadIdx.x;
  const size_t base = ((size_t)(b*2+h))*193*32;
  const float* __restrict__ kws = A.kws;
  const float* __restrict__ vws = A.vws;

  const int qrow = (t < 193) ? t : 192;
  float qreg[32], acc[32];
  {
    const float* qp = A.qws + base + qrow*32;
    #pragma unroll
    for (int d=0; d<32; d++){ qreg[d] = qp[d]; acc[d] = 0.f; }
  }
  float m = -1e30f, lsum = 0.f;
  for (int j=0; j<193; ++j){
    const float* kr = kws + base + j*32;   // wave-uniform address
    const float* vr = vws + base + j*32;
    float s = 0.f;
    #pragma unroll
    for (int d=0; d<32; d++) s += qreg[d]*kr[d];
    s *= 0.17677669529663687f;             // 1/sqrt(32)
    float mn = fmaxf(m, s);
    float al = __expf(m - mn);
    float p  = __expf(s - mn);
    lsum = lsum*al + p;
    #pragma unroll
    for (int d=0; d<32; d++) acc[d] = acc[d]*al + p*vr[d];
    m = mn;
  }
  if (t < 193){
    float inv = 1.f/lsum;
    size_t G = (size_t)b*193 + t;
    #pragma unroll
    for (int d=0; d<32; d++) A.attws[G*64 + h*32 + d] = f2b(acc[d]*inv);
  }
}

// ------------- Z1 = state+attn ; Z2 = LN(Z1) -> z2ws (bf16) -----------------
__global__ __launch_bounds__(256) void k_ln1(Args A){
  const int t = threadIdx.x, w = t>>6, l = t&63;
  const int G = blockIdx.x*4 + w;          // grid NROW/4 covers all rows
  float z1 = A.state[(size_t)G*64 + l] + b2f(A.attws[(size_t)G*64 + l]);
  float s = z1, sq = z1*z1;
  #pragma unroll
  for (int off=32; off>=1; off>>=1){ s += __shfl_xor(s,off); sq += __shfl_xor(sq,off); }
  float mean = s*(1.f/64.f);
  float var  = fmaxf(sq*(1.f/64.f) - mean*mean, 0.f);
  float z2 = (z1-mean)*rsqrtf(var+1e-5f)*A.g1[l] + A.be1[l];
  A.z2ws[(size_t)G*64 + l] = f2b(z2);
}

// ------------- fused FFN: gelu(Z2@W1+b1)@W2 + b2 + state + attn -> out ------
#define LZ2 72    // z2 tile padded stride
#define LZ3 264   // z3 tile padded stride
__global__ __launch_bounds__(256) void k_ffn(Args A){
  const int mb = blockIdx.x, t = threadIdx.x, w = t>>6, l = t&63, lr = l&15, lq = l>>4;
  __shared__ __align__(16) ushort_t z2t[64*LZ2];
  __shared__ __align__(16) ushort_t z3t[64*LZ3];

  #pragma unroll
  for (int i=0;i<2;i++){
    int p = i*2048 + t*8; int row = p>>6, col = p&63;
    *(ushortx8*)(z2t + row*LZ2 + col) = *(const ushortx8*)(A.z2ws + (size_t)mb*4096 + p);
  }
  __syncthreads();

  // FFN1: 64x256, K=64. wave w covers cols 64w..64w+63 (4 16-col tiles)
  floatx4 acc[4][4];
  #pragma unroll
  for (int jj=0;jj<4;jj++)
    #pragma unroll
    for (int ra=0;ra<4;ra++) acc[jj][ra] = floatx4{0.f,0.f,0.f,0.f};
  #pragma unroll
  for (int kc=0;kc<2;kc++){
    short8 a[4], b[4];
    #pragma unroll
    for (int ra=0;ra<4;ra++) a[ra] = *(const short8*)(z2t + (16*ra+lr)*LZ2 + kc*32 + lq*8);
    #pragma unroll
    for (int jj=0;jj<4;jj++) b[jj] = *(const short8*)(A.w1T + (size_t)(64*w + 16*jj + lr)*64 + kc*32 + lq*8);
    #pragma unroll
    for (int jj=0;jj<4;jj++)
      #pragma unroll
      for (int ra=0;ra<4;ra++)
        acc[jj][ra] = __builtin_amdgcn_mfma_f32_16x16x32_bf16(a[ra], b[jj], acc[jj][ra], 0,0,0);
  }
  #pragma unroll
  for (int jj=0;jj<4;jj++){
    int col = 64*w + 16*jj + lr;
    float bb = A.bl1[col];
    #pragma unroll
    for (int ra=0;ra<4;ra++)
      #pragma unroll
      for (int r=0;r<4;r++){
        int row = 16*ra + lq*4 + r;
        float x = acc[jj][ra][r] + bb;
        float gl = 0.5f*x*(1.0f + erff(x*0.70710678118654752f));
        z3t[row*LZ3 + col] = f2b(gl);
      }
  }
  __syncthreads();

  // FFN2: 64x64, K=256. wave w covers cols 16w..16w+15
  floatx4 o[4];
  #pragma unroll
  for (int ra=0;ra<4;ra++) o[ra] = floatx4{0.f,0.f,0.f,0.f};
  #pragma unroll
  for (int kc=0;kc<8;kc++){
    short8 a[4];
    short8 b = *(const short8*)(A.w2T + (size_t)(16*w + lr)*256 + kc*32 + lq*8);
    #pragma unroll
    for (int ra=0;ra<4;ra++) a[ra] = *(const short8*)(z3t + (16*ra+lr)*LZ3 + kc*32 + lq*8);
    #pragma unroll
    for (int ra=0;ra<4;ra++)
      o[ra] = __builtin_amdgcn_mfma_f32_16x16x32_bf16(a[ra], b, o[ra], 0,0,0);
  }
  int col = 16*w + lr;
  float bb = A.bl2[col];
  #pragma unroll
  for (int ra=0;ra<4;ra++)
    #pragma unroll
    for (int r=0;r<4;r++){
      int row = 16*ra + lq*4 + r;
      size_t idx = (size_t)(mb*64+row)*64 + col;
      A.out[idx] = o[ra][r] + bb + A.state[idx] + b2f(A.attws[idx]);  // fp32 store
    }
}

extern "C" void kernel_launch(void* const* d_in, const int* in_sizes, int n_in,
                              void* d_out, int out_size, void* d_ws, size_t ws_size,
                              hipStream_t stream){
  (void)in_sizes; (void)n_in; (void)out_size; (void)ws_size;
  Args A;
  A.state = (const float*)d_in[0];
  A.C0=(const float*)d_in[1]; A.C1=(const float*)d_in[2]; A.C2=(const float*)d_in[3];
  A.C3=(const float*)d_in[4]; A.C4=(const float*)d_in[5]; A.C5=(const float*)d_in[6];
  A.Wq=(const float*)d_in[7];  A.Wk=(const float*)d_in[8];  A.Wv=(const float*)d_in[9];
  A.bq=(const float*)d_in[10]; A.bk=(const float*)d_in[11]; A.bv=(const float*)d_in[12];
  A.WCq=(const float*)d_in[13]; A.WCk=(const float*)d_in[14]; A.WCv=(const float*)d_in[15];
  A.bCq=(const float*)d_in[16]; A.bCk=(const float*)d_in[17]; A.bCv=(const float*)d_in[18];
  A.gQE=(const float*)d_in[19]; A.beQE=(const float*)d_in[20];
  A.gKE=(const float*)d_in[21]; A.beKE=(const float*)d_in[22];
  A.gVE=(const float*)d_in[23]; A.beVE=(const float*)d_in[24];
  A.gQH=(const float*)d_in[25]; A.beQH=(const float*)d_in[26];
  A.gKH=(const float*)d_in[27]; A.beKH=(const float*)d_in[28];
  A.gVH=(const float*)d_in[29]; A.beVH=(const float*)d_in[30];
  A.g1=(const float*)d_in[31]; A.be1=(const float*)d_in[32];
  A.W1=(const float*)d_in[33]; A.bl1=(const float*)d_in[34];
  A.W2=(const float*)d_in[35]; A.bl2=(const float*)d_in[36];

  // workspace layout (~51.3 MB)
  char* ws = (char*)d_ws;
  size_t off = 0;
  const size_t rowf = (size_t)NROW*64*sizeof(float);       // 12.65 MB
  const size_t rowh = (size_t)NROW*64*2;                   // 6.32 MB
  A.qws  = (float*)(ws+off); off += rowf;
  A.kws  = (float*)(ws+off); off += rowf;
  A.vws  = (float*)(ws+off); off += rowf;
  A.attws= (ushort_t*)(ws+off); off += rowh;
  A.z2ws = (ushort_t*)(ws+off); off += rowh;
  A.weT  = (ushort_t*)(ws+off); off += 192*64*2;
  A.whT  = (ushort_t*)(ws+off); off += (size_t)192*1536*2;
  A.w1T  = (ushort_t*)(ws+off); off += 256*64*2;
  A.w2T  = (ushort_t*)(ws+off); off += 64*256*2;
  A.out  = (float*)d_out;

  k_prep <<<dim3(256),    dim3(256), 0, stream>>>(A);
  k_proj <<<dim3(MT),     dim3(256), 0, stream>>>(A);
  k_attn <<<dim3(256,2),  dim3(256), 0, stream>>>(A);
  k_ln1  <<<dim3(NROW/4), dim3(256), 0, stream>>>(A);
  k_ffn  <<<dim3(MT),     dim3(256), 0, stream>>>(A);
}

// Round 3
// 636.819 us; speedup vs baseline: 1.2958x; 1.1612x over previous
//
#include <hip/hip_runtime.h>
#include <math.h>

typedef unsigned short ushort_t;
typedef __attribute__((ext_vector_type(8))) short short8;
typedef __attribute__((ext_vector_type(4))) float floatx4;
typedef __attribute__((ext_vector_type(8))) unsigned short ushortx8;

#define NROW 49408   // B*L = 256*193
#define MT   772     // NROW/64

__device__ __forceinline__ float b2f(ushort_t u){
  union { float f; unsigned int i; } v; v.i = ((unsigned int)u) << 16; return v.f;
}
__device__ __forceinline__ ushort_t f2b(float f){
  unsigned int i = __float_as_uint(f);
  unsigned int r = (i + 0x7FFFu + ((i >> 16) & 1u)) >> 16;
  return (ushort_t)r;
}

struct Args {
  const float *state,*C0,*C1,*C2,*C3,*C4,*C5;
  const float *Wq,*Wk,*Wv,*bq,*bk,*bv;
  const float *WCq,*WCk,*WCv,*bCq,*bCk,*bCv;
  const float *gQE,*beQE,*gKE,*beKE,*gVE,*beVE;
  const float *gQH,*beQH,*gKH,*beKH,*gVH,*beVH;
  const float *g1,*be1,*W1,*bl1,*W2,*bl2;
  float *qws,*kws,*vws;           // fp32 [B*H, 193, 32]
  ushort_t *attws;                // bf16 [NROW,64]
  ushort_t *weT,*whT,*w1T,*w2T;   // bf16 pre-transposed weights
  float *out;                     // fp32 [NROW,64]  <-- output IS float32
};

// ------------- weight convert+transpose ---------------------------------
// weT/whT layout: K-panel-contiguous [kc32][192 n][32 kk] (kc32 = K/32 panel)
__global__ __launch_bounds__(256) void k_prep(Args A){
  int i = blockIdx.x*256 + threadIdx.x;
  int stride = gridDim.x*256;
  const float* We[3] = {A.Wq, A.Wk, A.Wv};
  const float* Wh[3] = {A.WCq, A.WCk, A.WCv};
  for (int p=i; p<2*6144; p+=stride){
    int kc = p / 6144, r = p - kc*6144, n = r >> 5, kk = r & 31;
    A.weT[p] = f2b(We[n>>6][(kc*32+kk)*64 + (n&63)]);
  }
  for (int p=i; p<48*6144; p+=stride){
    int kc = p / 6144, r = p - kc*6144, n = r >> 5, kk = r & 31;
    A.whT[p] = f2b(Wh[n>>6][(kc*32+kk)*64 + (n&63)]);
  }
  for (int p=i; p<256*64; p+=stride){ int n=p>>6, k=p&63; A.w1T[p] = f2b(A.W1[k*256 + n]); }   // w1T[256][64]
  for (int p=i; p<64*256; p+=stride){ int n=p>>8, k=p&255; A.w2T[p] = f2b(A.W2[k*64 + n]); }   // w2T[64][256]
}

// ------------- projections + LN-gate -> q/k/v ws ---------------------------
// BK=64 pipeline, 25 steps (24 H + 1 E). A double-buffered in LDS; B direct
// global->reg 1 step ahead; A reg-staged 2 steps ahead. K-loop barriers are
// raw s_barrier + lgkmcnt(0) ONLY (no vmcnt drain) so prefetch loads stay in
// flight across barriers. Issue order per step s: B(s+1), A(s+2), MFMA(b(s)),
// storeA(s+1) -> counted vmcnt, no transitive forcing (in-order retirement).
#define LDA 72   // padded LDS stride (64+8 ushorts), 144B row, 16B-aligned
__global__ __launch_bounds__(256,2) void k_proj(Args A){
  const int mb = blockIdx.x;
  const int t  = threadIdx.x;
  const int w  = t >> 6;
  const int l  = t & 63;
  const int lr = l & 15;
  const int lq = l >> 4;
  const int arow = t >> 2, aseg = t & 3;   // A stage: row 0..63, 16-float seg

  struct __align__(16) SM {
    union {
      ushort_t Abuf[2][64*LDA];                         // 18432 B
      struct { float E[64][65]; float Hh[64][65]; } ln; // 33280 B (epilogue)
    };
  };
  __shared__ SM sm;

  floatx4 accH[3][4];
  floatx4 accE[3][4];
  #pragma unroll
  for (int jj=0;jj<3;jj++)
    #pragma unroll
    for (int ra=0;ra<4;ra++){ accH[jj][ra] = floatx4{0.f,0.f,0.f,0.f}; accE[jj][ra] = floatx4{0.f,0.f,0.f,0.f}; }

  // tile k in 0..24: k<24 = H (C[k>>2], col block (k&3)*64), k==24 = E (state)
  auto loadA = [&](int k, float4* f){
    const float* src;
    if (k < 24){
      int sel = k >> 2;                    // 0..5, wave-uniform
      const float* cb = A.C0;
      if (sel==1) cb=A.C1; else if (sel==2) cb=A.C2; else if (sel==3) cb=A.C3;
      else if (sel==4) cb=A.C4; else if (sel==5) cb=A.C5;
      src = cb + (size_t)(mb*64 + arow)*256 + (k&3)*64 + aseg*16;
    } else {
      src = A.state + (size_t)(mb*64 + arow)*64 + aseg*16;
    }
    f[0] = ((const float4*)src)[0];
    f[1] = ((const float4*)src)[1];
    f[2] = ((const float4*)src)[2];
    f[3] = ((const float4*)src)[3];
  };
  auto loadB = [&](int k, short8* b){
    const ushort_t* bp = (k < 24) ? (A.whT + (size_t)(2*k)*6144) : A.weT;
    #pragma unroll
    for (int ks=0; ks<2; ++ks)
      #pragma unroll
      for (int jj=0; jj<3; ++jj)
        b[ks*3+jj] = *(const short8*)(bp + ks*6144 + (48*w + 16*jj + lr)*32 + lq*8);
  };
  auto storeA = [&](int buf, const float4* f){
    ushortx8 u0, u1;
    u0[0]=f2b(f[0].x); u0[1]=f2b(f[0].y); u0[2]=f2b(f[0].z); u0[3]=f2b(f[0].w);
    u0[4]=f2b(f[1].x); u0[5]=f2b(f[1].y); u0[6]=f2b(f[1].z); u0[7]=f2b(f[1].w);
    u1[0]=f2b(f[2].x); u1[1]=f2b(f[2].y); u1[2]=f2b(f[2].z); u1[3]=f2b(f[2].w);
    u1[4]=f2b(f[3].x); u1[5]=f2b(f[3].y); u1[6]=f2b(f[3].z); u1[7]=f2b(f[3].w);
    ushort_t* p = sm.Abuf[buf] + arow*LDA + aseg*16;
    *(ushortx8*)p = u0;
    *(ushortx8*)(p+8) = u1;
  };
  auto mfmaStep = [&](int cur, const short8* b, floatx4 (&acc)[3][4]){
    #pragma unroll
    for (int ks=0; ks<2; ++ks){
      short8 a[4];
      #pragma unroll
      for (int ra=0;ra<4;ra++)
        a[ra] = *(const short8*)(sm.Abuf[cur] + (16*ra + lr)*LDA + ks*32 + lq*8);
      #pragma unroll
      for (int jj=0;jj<3;jj++)
        #pragma unroll
        for (int ra=0;ra<4;ra++)
          acc[jj][ra] = __builtin_amdgcn_mfma_f32_16x16x32_bf16(a[ra], b[ks*3+jj], acc[jj][ra], 0,0,0);
    }
  };

  float4 rA[4], rB[4];
  short8 bA[6], bB[6];

  // prologue
  loadB(0, bA);        // b(0)
  loadA(0, rB);        // tile 0 (transient)
  loadA(1, rA);        // tile 1
  storeA(0, rB);       // counted vmcnt: rA stays in flight (drained by syncthreads, prologue-only)
  __syncthreads();

  // main loop: steps s and s+1 per iteration; even step reads buf0, odd buf1
  for (int kc = 0; kc < 24; kc += 2){
    // step s=kc (even)
    loadB(kc+1, bB);
    loadA(kc+2, rB);                    // kc+2 <= 24 always here
    mfmaStep(0, bA, accH);
    storeA(1, rA);                      // tile kc+1 -> buf1 (vmcnt counted)
    asm volatile("s_waitcnt lgkmcnt(0)" ::: "memory");
    __builtin_amdgcn_s_barrier();
    __builtin_amdgcn_sched_barrier(0);
    // step s=kc+1 (odd)
    loadB(kc+2, bA);
    if (kc+3 <= 24) loadA(kc+3, rA);
    mfmaStep(1, bB, accH);
    storeA(0, rB);                      // tile kc+2 -> buf0
    asm volatile("s_waitcnt lgkmcnt(0)" ::: "memory");
    __builtin_amdgcn_s_barrier();
    __builtin_amdgcn_sched_barrier(0);
  }
  // step 24 (E): buf0 holds tile 24, bA holds b(24)
  mfmaStep(0, bA, accE);
  __syncthreads();   // full drain OK once; all waves done reading Abuf before union reuse

  // ---- epilogue: per group g in {q,k,v}: bias, LN(E)*LN(H), store ----
  const float* bEs[3]  = {A.bq,  A.bk,  A.bv};
  const float* bHs[3]  = {A.bCq, A.bCk, A.bCv};
  const float* gEs[3]  = {A.gQE, A.gKE, A.gVE};
  const float* beEs[3] = {A.beQE,A.beKE,A.beVE};
  const float* gHs[3]  = {A.gQH, A.gKH, A.gVH};
  const float* beHs[3] = {A.beQH,A.beKH,A.beVH};
  float* outw[3] = {A.qws, A.kws, A.vws};

  for (int g=0; g<3; ++g){
    #pragma unroll
    for (int jj=0;jj<3;jj++){
      int jg = 3*w + jj;                    // global 16-col tile 0..11
      if ((jg >> 2) == g){
        int colL = (jg & 3)*16 + lr;        // col within group, 0..63
        float be_ = bEs[g][colL];
        float bh_ = bHs[g][colL];
        #pragma unroll
        for (int ra=0;ra<4;ra++)
          #pragma unroll
          for (int r=0;r<4;r++){
            int row = 16*ra + lq*4 + r;
            sm.ln.E[row][colL]  = accE[jj][ra][r] + be_;
            sm.ln.Hh[row][colL] = accH[jj][ra][r] + bh_;
          }
      }
    }
    __syncthreads();
    {
      int r = t >> 2, q4 = t & 3;
      float sE=0.f, ssE=0.f, sH=0.f, ssH=0.f;
      #pragma unroll
      for (int c=0;c<16;c++){
        float e = sm.ln.E[r][q4*16+c];  sE += e; ssE += e*e;
        float h = sm.ln.Hh[r][q4*16+c]; sH += h; ssH += h*h;
      }
      sE  += __shfl_xor(sE,1);  sE  += __shfl_xor(sE,2);
      ssE += __shfl_xor(ssE,1); ssE += __shfl_xor(ssE,2);
      sH  += __shfl_xor(sH,1);  sH  += __shfl_xor(sH,2);
      ssH += __shfl_xor(ssH,1); ssH += __shfl_xor(ssH,2);
      float mE = sE*(1.f/64.f), vE = fmaxf(ssE*(1.f/64.f) - mE*mE, 0.f);
      float mH = sH*(1.f/64.f), vH = fmaxf(ssH*(1.f/64.f) - mH*mH, 0.f);
      float rE = rsqrtf(vE + 1e-5f), rH = rsqrtf(vH + 1e-5f);
      int G  = mb*64 + r;
      int bb = G / 193, lp = G - bb*193;
      float* ow = outw[g];
      #pragma unroll
      for (int c=0;c<16;c++){
        int cc = q4*16 + c;
        float e = (sm.ln.E[r][cc]-mE)*rE*gEs[g][cc] + beEs[g][cc];
        float h = (sm.ln.Hh[r][cc]-mH)*rH*gHs[g][cc] + beHs[g][cc];
        int hd = cc >> 5, d = cc & 31;
        ow[((size_t)(bb*2+hd)*193 + lp)*32 + d] = e*h;
      }
    }
    __syncthreads();
  }
}

// ------------- attention: one block per (b,h), query-per-thread -------------
__global__ __launch_bounds__(256) void k_attn(Args A){
  const int b = blockIdx.x, h = blockIdx.y;
  const int t = threadIdx.x;
  const size_t base = ((size_t)(b*2+h))*193*32;
  const float* __restrict__ kws = A.kws;
  const float* __restrict__ vws = A.vws;

  const int qrow = (t < 193) ? t : 192;
  float qreg[32], acc[32];
  {
    const float* qp = A.qws + base + qrow*32;
    #pragma unroll
    for (int d=0; d<32; d++){ qreg[d] = qp[d]; acc[d] = 0.f; }
  }
  float m = -1e30f, lsum = 0.f;
  for (int j=0; j<193; ++j){
    const float* kr = kws + base + j*32;   // wave-uniform address
    const float* vr = vws + base + j*32;
    float s = 0.f;
    #pragma unroll
    for (int d=0; d<32; d++) s += qreg[d]*kr[d];
    s *= 0.17677669529663687f;             // 1/sqrt(32)
    float mn = fmaxf(m, s);
    float al = __expf(m - mn);
    float p  = __expf(s - mn);
    lsum = lsum*al + p;
    #pragma unroll
    for (int d=0; d<32; d++) acc[d] = acc[d]*al + p*vr[d];
    m = mn;
  }
  if (t < 193){
    float inv = 1.f/lsum;
    size_t G = (size_t)b*193 + t;
    #pragma unroll
    for (int d=0; d<32; d++) A.attws[G*64 + h*32 + d] = f2b(acc[d]*inv);
  }
}

// ------------- fused: Z1=state+attn; Z2=LN(Z1); gelu(Z2@W1+b1)@W2+b2+Z1 -----
#define LZ1 68    // z1 f32 tile padded stride (272B, 16B-aligned)
#define LZ2 72    // z2 tile padded stride
#define LZ3 264   // z3 tile padded stride
__global__ __launch_bounds__(256) void k_ffn(Args A){
  const int mb = blockIdx.x, t = threadIdx.x, w = t>>6, l = t&63, lr = l&15, lq = l>>4;
  __shared__ __align__(16) float    z1t[64*LZ1];
  __shared__ __align__(16) ushort_t z2t[64*LZ2];
  __shared__ __align__(16) ushort_t z3t[64*LZ3];

  // prologue: z1 = state + attn (f32) into LDS
  {
    int row = t >> 2, seg = t & 3;
    const float* sp    = A.state + (size_t)(mb*64+row)*64 + seg*16;
    const ushort_t* ap = A.attws + (size_t)(mb*64+row)*64 + seg*16;
    float4 s0=((const float4*)sp)[0], s1=((const float4*)sp)[1],
           s2=((const float4*)sp)[2], s3=((const float4*)sp)[3];
    ushortx8 a0 = *(const ushortx8*)ap, a1 = *(const ushortx8*)(ap+8);
    float4 z0, z1, z2, z3;
    z0.x=s0.x+b2f(a0[0]); z0.y=s0.y+b2f(a0[1]); z0.z=s0.z+b2f(a0[2]); z0.w=s0.w+b2f(a0[3]);
    z1.x=s1.x+b2f(a0[4]); z1.y=s1.y+b2f(a0[5]); z1.z=s1.z+b2f(a0[6]); z1.w=s1.w+b2f(a0[7]);
    z2.x=s2.x+b2f(a1[0]); z2.y=s2.y+b2f(a1[1]); z2.z=s2.z+b2f(a1[2]); z2.w=s2.w+b2f(a1[3]);
    z3.x=s3.x+b2f(a1[4]); z3.y=s3.y+b2f(a1[5]); z3.z=s3.z+b2f(a1[6]); z3.w=s3.w+b2f(a1[7]);
    float* zp = z1t + row*LZ1 + seg*16;
    ((float4*)zp)[0]=z0; ((float4*)zp)[1]=z1; ((float4*)zp)[2]=z2; ((float4*)zp)[3]=z3;
  }
  __syncthreads();

  // LN(z1) -> z2t (bf16); 4 threads per row
  {
    int r = t >> 2, q4 = t & 3;
    float s=0.f, ss=0.f;
    #pragma unroll
    for (int c=0;c<16;c++){ float v = z1t[r*LZ1 + q4*16 + c]; s += v; ss += v*v; }
    s  += __shfl_xor(s,1);  s  += __shfl_xor(s,2);
    ss += __shfl_xor(ss,1); ss += __shfl_xor(ss,2);
    float mean = s*(1.f/64.f);
    float var  = fmaxf(ss*(1.f/64.f) - mean*mean, 0.f);
    float rstd = rsqrtf(var + 1e-5f);
    ushortx8 u0, u1;
    #pragma unroll
    for (int c=0;c<16;c++){
      int cc = q4*16 + c;
      float z2v = (z1t[r*LZ1 + cc]-mean)*rstd*A.g1[cc] + A.be1[cc];
      if (c < 8) u0[c] = f2b(z2v); else u1[c-8] = f2b(z2v);
    }
    ushort_t* zp = z2t + r*LZ2 + q4*16;
    *(ushortx8*)zp = u0;
    *(ushortx8*)(zp+8) = u1;
  }
  __syncthreads();

  // FFN1: 64x256, K=64. wave w covers cols 64w..64w+63 (4 16-col tiles)
  floatx4 acc[4][4];
  #pragma unroll
  for (int jj=0;jj<4;jj++)
    #pragma unroll
    for (int ra=0;ra<4;ra++) acc[jj][ra] = floatx4{0.f,0.f,0.f,0.f};
  #pragma unroll
  for (int kc=0;kc<2;kc++){
    short8 a[4], b[4];
    #pragma unroll
    for (int ra=0;ra<4;ra++) a[ra] = *(const short8*)(z2t + (16*ra+lr)*LZ2 + kc*32 + lq*8);
    #pragma unroll
    for (int jj=0;jj<4;jj++) b[jj] = *(const short8*)(A.w1T + (size_t)(64*w + 16*jj + lr)*64 + kc*32 + lq*8);
    #pragma unroll
    for (int jj=0;jj<4;jj++)
      #pragma unroll
      for (int ra=0;ra<4;ra++)
        acc[jj][ra] = __builtin_amdgcn_mfma_f32_16x16x32_bf16(a[ra], b[jj], acc[jj][ra], 0,0,0);
  }
  #pragma unroll
  for (int jj=0;jj<4;jj++){
    int col = 64*w + 16*jj + lr;
    float bb = A.bl1[col];
    #pragma unroll
    for (int ra=0;ra<4;ra++)
      #pragma unroll
      for (int r=0;r<4;r++){
        int row = 16*ra + lq*4 + r;
        float x = acc[jj][ra][r] + bb;
        float gl = 0.5f*x*(1.0f + erff(x*0.70710678118654752f));
        z3t[row*LZ3 + col] = f2b(gl);
      }
  }
  __syncthreads();

  // FFN2: 64x64, K=256. wave w covers cols 16w..16w+15
  floatx4 o[4];
  #pragma unroll
  for (int ra=0;ra<4;ra++) o[ra] = floatx4{0.f,0.f,0.f,0.f};
  #pragma unroll
  for (int kc=0;kc<8;kc++){
    short8 a[4];
    short8 b = *(const short8*)(A.w2T + (size_t)(16*w + lr)*256 + kc*32 + lq*8);
    #pragma unroll
    for (int ra=0;ra<4;ra++) a[ra] = *(const short8*)(z3t + (16*ra+lr)*LZ3 + kc*32 + lq*8);
    #pragma unroll
    for (int ra=0;ra<4;ra++)
      o[ra] = __builtin_amdgcn_mfma_f32_16x16x32_bf16(a[ra], b, o[ra], 0,0,0);
  }
  int col = 16*w + lr;
  float bb = A.bl2[col];
  #pragma unroll
  for (int ra=0;ra<4;ra++)
    #pragma unroll
    for (int r=0;r<4;r++){
      int row = 16*ra + lq*4 + r;
      size_t idx = (size_t)(mb*64+row)*64 + col;
      A.out[idx] = o[ra][r] + bb + z1t[row*LZ1 + col];  // residual from LDS
    }
}

extern "C" void kernel_launch(void* const* d_in, const int* in_sizes, int n_in,
                              void* d_out, int out_size, void* d_ws, size_t ws_size,
                              hipStream_t stream){
  (void)in_sizes; (void)n_in; (void)out_size; (void)ws_size;
  Args A;
  A.state = (const float*)d_in[0];
  A.C0=(const float*)d_in[1]; A.C1=(const float*)d_in[2]; A.C2=(const float*)d_in[3];
  A.C3=(const float*)d_in[4]; A.C4=(const float*)d_in[5]; A.C5=(const float*)d_in[6];
  A.Wq=(const float*)d_in[7];  A.Wk=(const float*)d_in[8];  A.Wv=(const float*)d_in[9];
  A.bq=(const float*)d_in[10]; A.bk=(const float*)d_in[11]; A.bv=(const float*)d_in[12];
  A.WCq=(const float*)d_in[13]; A.WCk=(const float*)d_in[14]; A.WCv=(const float*)d_in[15];
  A.bCq=(const float*)d_in[16]; A.bCk=(const float*)d_in[17]; A.bCv=(const float*)d_in[18];
  A.gQE=(const float*)d_in[19]; A.beQE=(const float*)d_in[20];
  A.gKE=(const float*)d_in[21]; A.beKE=(const float*)d_in[22];
  A.gVE=(const float*)d_in[23]; A.beVE=(const float*)d_in[24];
  A.gQH=(const float*)d_in[25]; A.beQH=(const float*)d_in[26];
  A.gKH=(const float*)d_in[27]; A.beKH=(const float*)d_in[28];
  A.gVH=(const float*)d_in[29]; A.beVH=(const float*)d_in[30];
  A.g1=(const float*)d_in[31]; A.be1=(const float*)d_in[32];
  A.W1=(const float*)d_in[33]; A.bl1=(const float*)d_in[34];
  A.W2=(const float*)d_in[35]; A.bl2=(const float*)d_in[36];

  // workspace layout (~45 MB)
  char* ws = (char*)d_ws;
  size_t off = 0;
  const size_t rowf = (size_t)NROW*64*sizeof(float);       // 12.65 MB
  const size_t rowh = (size_t)NROW*64*2;                   // 6.32 MB
  A.qws  = (float*)(ws+off); off += rowf;
  A.kws  = (float*)(ws+off); off += rowf;
  A.vws  = (float*)(ws+off); off += rowf;
  A.attws= (ushort_t*)(ws+off); off += rowh;
  A.weT  = (ushort_t*)(ws+off); off += 192*64*2;
  A.whT  = (ushort_t*)(ws+off); off += (size_t)192*1536*2;
  A.w1T  = (ushort_t*)(ws+off); off += 256*64*2;
  A.w2T  = (ushort_t*)(ws+off); off += 64*256*2;
  A.out  = (float*)d_out;

  k_prep <<<dim3(256),    dim3(256), 0, stream>>>(A);
  k_proj <<<dim3(MT),     dim3(256), 0, stream>>>(A);
  k_attn <<<dim3(256,2),  dim3(256), 0, stream>>>(A);
  k_ffn  <<<dim3(MT),     dim3(256), 0, stream>>>(A);
}

// Round 4
// 522.983 us; speedup vs baseline: 1.5778x; 1.2177x over previous
//
#include <hip/hip_runtime.h>
#include <math.h>

typedef unsigned short ushort_t;
typedef __attribute__((ext_vector_type(8))) short short8;
typedef __attribute__((ext_vector_type(4))) float floatx4;
typedef __attribute__((ext_vector_type(8))) unsigned short ushortx8;

#define NROW 49408   // B*L = 256*193
#define MT   772     // NROW/64

__device__ __forceinline__ float b2f(ushort_t u){
  union { float f; unsigned int i; } v; v.i = ((unsigned int)u) << 16; return v.f;
}
__device__ __forceinline__ ushort_t f2b(float f){
  unsigned int i = __float_as_uint(f);
  unsigned int r = (i + 0x7FFFu + ((i >> 16) & 1u)) >> 16;
  return (ushort_t)r;
}

struct Args {
  const float *state,*C0,*C1,*C2,*C3,*C4,*C5;
  const float *Wq,*Wk,*Wv,*bq,*bk,*bv;
  const float *WCq,*WCk,*WCv,*bCq,*bCk,*bCv;
  const float *gQE,*beQE,*gKE,*beKE,*gVE,*beVE;
  const float *gQH,*beQH,*gKH,*beKH,*gVH,*beVH;
  const float *g1,*be1,*W1,*bl1,*W2,*bl2;
  float *qws,*kws,*vws;           // fp32 [B*H, 193, 32]
  ushort_t *attws;                // bf16 [NROW,64]
  ushort_t *weT,*whT,*w1T,*w2T;   // bf16 pre-transposed weights
  float *out;                     // fp32 [NROW,64]  <-- output IS float32
};

// ------------- weight convert+transpose ---------------------------------
// weT/whT layout: K-panel-contiguous [kc32][192 n][32 kk] (kc32 = K/32 panel)
__global__ __launch_bounds__(256) void k_prep(Args A){
  int i = blockIdx.x*256 + threadIdx.x;
  int stride = gridDim.x*256;
  const float* We[3] = {A.Wq, A.Wk, A.Wv};
  const float* Wh[3] = {A.WCq, A.WCk, A.WCv};
  for (int p=i; p<2*6144; p+=stride){
    int kc = p / 6144, r = p - kc*6144, n = r >> 5, kk = r & 31;
    A.weT[p] = f2b(We[n>>6][(kc*32+kk)*64 + (n&63)]);
  }
  for (int p=i; p<48*6144; p+=stride){
    int kc = p / 6144, r = p - kc*6144, n = r >> 5, kk = r & 31;
    A.whT[p] = f2b(Wh[n>>6][(kc*32+kk)*64 + (n&63)]);
  }
  for (int p=i; p<256*64; p+=stride){ int n=p>>6, k=p&63; A.w1T[p] = f2b(A.W1[k*256 + n]); }   // w1T[256][64]
  for (int p=i; p<64*256; p+=stride){ int n=p>>8, k=p&255; A.w2T[p] = f2b(A.W2[k*64 + n]); }   // w2T[64][256]
}

// ------------- projections + LN-gate -> q/k/v ws ---------------------------
// BK=64 pipeline, 25 steps (24 H + 1 E). A double-buffered in LDS; B direct
// global->reg 1 step ahead; A reg-staged 2 steps ahead. K-loop barriers are
// raw s_barrier + lgkmcnt(0) ONLY (no vmcnt drain) so prefetch loads stay in
// flight across barriers.
#define LDA 72   // padded LDS stride (64+8 ushorts), 144B row, 16B-aligned
__global__ __launch_bounds__(256,2) void k_proj(Args A){
  const int mb = blockIdx.x;
  const int t  = threadIdx.x;
  const int w  = t >> 6;
  const int l  = t & 63;
  const int lr = l & 15;
  const int lq = l >> 4;
  const int arow = t >> 2, aseg = t & 3;   // A stage: row 0..63, 16-float seg

  struct __align__(16) SM {
    union {
      ushort_t Abuf[2][64*LDA];                         // 18432 B
      struct { float E[64][65]; float Hh[64][65]; } ln; // 33280 B (epilogue)
    };
  };
  __shared__ SM sm;

  floatx4 accH[3][4];
  floatx4 accE[3][4];
  #pragma unroll
  for (int jj=0;jj<3;jj++)
    #pragma unroll
    for (int ra=0;ra<4;ra++){ accH[jj][ra] = floatx4{0.f,0.f,0.f,0.f}; accE[jj][ra] = floatx4{0.f,0.f,0.f,0.f}; }

  // tile k in 0..24: k<24 = H (C[k>>2], col block (k&3)*64), k==24 = E (state)
  auto loadA = [&](int k, float4* f){
    const float* src;
    if (k < 24){
      int sel = k >> 2;                    // 0..5, wave-uniform
      const float* cb = A.C0;
      if (sel==1) cb=A.C1; else if (sel==2) cb=A.C2; else if (sel==3) cb=A.C3;
      else if (sel==4) cb=A.C4; else if (sel==5) cb=A.C5;
      src = cb + (size_t)(mb*64 + arow)*256 + (k&3)*64 + aseg*16;
    } else {
      src = A.state + (size_t)(mb*64 + arow)*64 + aseg*16;
    }
    f[0] = ((const float4*)src)[0];
    f[1] = ((const float4*)src)[1];
    f[2] = ((const float4*)src)[2];
    f[3] = ((const float4*)src)[3];
  };
  auto loadB = [&](int k, short8* b){
    const ushort_t* bp = (k < 24) ? (A.whT + (size_t)(2*k)*6144) : A.weT;
    #pragma unroll
    for (int ks=0; ks<2; ++ks)
      #pragma unroll
      for (int jj=0; jj<3; ++jj)
        b[ks*3+jj] = *(const short8*)(bp + ks*6144 + (48*w + 16*jj + lr)*32 + lq*8);
  };
  auto storeA = [&](int buf, const float4* f){
    ushortx8 u0, u1;
    u0[0]=f2b(f[0].x); u0[1]=f2b(f[0].y); u0[2]=f2b(f[0].z); u0[3]=f2b(f[0].w);
    u0[4]=f2b(f[1].x); u0[5]=f2b(f[1].y); u0[6]=f2b(f[1].z); u0[7]=f2b(f[1].w);
    u1[0]=f2b(f[2].x); u1[1]=f2b(f[2].y); u1[2]=f2b(f[2].z); u1[3]=f2b(f[2].w);
    u1[4]=f2b(f[3].x); u1[5]=f2b(f[3].y); u1[6]=f2b(f[3].z); u1[7]=f2b(f[3].w);
    ushort_t* p = sm.Abuf[buf] + arow*LDA + aseg*16;
    *(ushortx8*)p = u0;
    *(ushortx8*)(p+8) = u1;
  };
  auto mfmaStep = [&](int cur, const short8* b, floatx4 (&acc)[3][4]){
    #pragma unroll
    for (int ks=0; ks<2; ++ks){
      short8 a[4];
      #pragma unroll
      for (int ra=0;ra<4;ra++)
        a[ra] = *(const short8*)(sm.Abuf[cur] + (16*ra + lr)*LDA + ks*32 + lq*8);
      #pragma unroll
      for (int jj=0;jj<3;jj++)
        #pragma unroll
        for (int ra=0;ra<4;ra++)
          acc[jj][ra] = __builtin_amdgcn_mfma_f32_16x16x32_bf16(a[ra], b[ks*3+jj], acc[jj][ra], 0,0,0);
    }
  };

  float4 rA[4], rB[4];
  short8 bA[6], bB[6];

  // prologue
  loadB(0, bA);        // b(0)
  loadA(0, rB);        // tile 0 (transient)
  loadA(1, rA);        // tile 1
  storeA(0, rB);       // counted vmcnt: rA stays in flight
  __syncthreads();

  // main loop: steps s and s+1 per iteration; even step reads buf0, odd buf1
  for (int kc = 0; kc < 24; kc += 2){
    // step s=kc (even)
    loadB(kc+1, bB);
    loadA(kc+2, rB);                    // kc+2 <= 24 always here
    mfmaStep(0, bA, accH);
    storeA(1, rA);                      // tile kc+1 -> buf1 (vmcnt counted)
    asm volatile("s_waitcnt lgkmcnt(0)" ::: "memory");
    __builtin_amdgcn_s_barrier();
    __builtin_amdgcn_sched_barrier(0);
    // step s=kc+1 (odd)
    loadB(kc+2, bA);
    if (kc+3 <= 24) loadA(kc+3, rA);
    mfmaStep(1, bB, accH);
    storeA(0, rB);                      // tile kc+2 -> buf0
    asm volatile("s_waitcnt lgkmcnt(0)" ::: "memory");
    __builtin_amdgcn_s_barrier();
    __builtin_amdgcn_sched_barrier(0);
  }
  // step 24 (E): buf0 holds tile 24, bA holds b(24)
  mfmaStep(0, bA, accE);
  __syncthreads();   // full drain OK once; all waves done reading Abuf before union reuse

  // ---- epilogue: per group g in {q,k,v}: bias, LN(E)*LN(H), store ----
  const float* bEs[3]  = {A.bq,  A.bk,  A.bv};
  const float* bHs[3]  = {A.bCq, A.bCk, A.bCv};
  const float* gEs[3]  = {A.gQE, A.gKE, A.gVE};
  const float* beEs[3] = {A.beQE,A.beKE,A.beVE};
  const float* gHs[3]  = {A.gQH, A.gKH, A.gVH};
  const float* beHs[3] = {A.beQH,A.beKH,A.beVH};
  float* outw[3] = {A.qws, A.kws, A.vws};

  for (int g=0; g<3; ++g){
    #pragma unroll
    for (int jj=0;jj<3;jj++){
      int jg = 3*w + jj;                    // global 16-col tile 0..11
      if ((jg >> 2) == g){
        int colL = (jg & 3)*16 + lr;        // col within group, 0..63
        float be_ = bEs[g][colL];
        float bh_ = bHs[g][colL];
        #pragma unroll
        for (int ra=0;ra<4;ra++)
          #pragma unroll
          for (int r=0;r<4;r++){
            int row = 16*ra + lq*4 + r;
            sm.ln.E[row][colL]  = accE[jj][ra][r] + be_;
            sm.ln.Hh[row][colL] = accH[jj][ra][r] + bh_;
          }
      }
    }
    __syncthreads();
    {
      int r = t >> 2, q4 = t & 3;
      float sE=0.f, ssE=0.f, sH=0.f, ssH=0.f;
      #pragma unroll
      for (int c=0;c<16;c++){
        float e = sm.ln.E[r][q4*16+c];  sE += e; ssE += e*e;
        float h = sm.ln.Hh[r][q4*16+c]; sH += h; ssH += h*h;
      }
      sE  += __shfl_xor(sE,1);  sE  += __shfl_xor(sE,2);
      ssE += __shfl_xor(ssE,1); ssE += __shfl_xor(ssE,2);
      sH  += __shfl_xor(sH,1);  sH  += __shfl_xor(sH,2);
      ssH += __shfl_xor(ssH,1); ssH += __shfl_xor(ssH,2);
      float mE = sE*(1.f/64.f), vE = fmaxf(ssE*(1.f/64.f) - mE*mE, 0.f);
      float mH = sH*(1.f/64.f), vH = fmaxf(ssH*(1.f/64.f) - mH*mH, 0.f);
      float rE = rsqrtf(vE + 1e-5f), rH = rsqrtf(vH + 1e-5f);
      int G  = mb*64 + r;
      int bb = G / 193, lp = G - bb*193;
      float* ow = outw[g];
      #pragma unroll
      for (int c=0;c<16;c++){
        int cc = q4*16 + c;
        float e = (sm.ln.E[r][cc]-mE)*rE*gEs[g][cc] + beEs[g][cc];
        float h = (sm.ln.Hh[r][cc]-mH)*rH*gHs[g][cc] + beHs[g][cc];
        int hd = cc >> 5, d = cc & 31;
        ow[((size_t)(bb*2+hd)*193 + lp)*32 + d] = e*h;
      }
    }
    __syncthreads();
  }
}

// ------------- attention: one block per (b,h), K/V staged in LDS ------------
// K/V rows read as same-address LDS broadcasts (conflict-free) instead of
// dependent L2 round-trips; defer-max (THR=8) online softmax: acc += p*v only,
// rescale only on (rare) max growth > THR. f32 throughout (no precision change).
__global__ __launch_bounds__(256) void k_attn(Args A){
  const int b = blockIdx.x, h = blockIdx.y;
  const int t = threadIdx.x;
  const size_t base = ((size_t)(b*2+h))*193*32;

  __shared__ __align__(16) float Kl[193*32];
  __shared__ __align__(16) float Vl[193*32];
  {
    const float4* ks = (const float4*)(A.kws + base);
    const float4* vs = (const float4*)(A.vws + base);
    float4* kd = (float4*)Kl;
    float4* vd = (float4*)Vl;
    for (int i = t; i < 1544; i += 256){ kd[i] = ks[i]; vd[i] = vs[i]; }
  }

  const int qrow = (t < 193) ? t : 192;
  float4 qv[8], av[8];
  {
    const float4* qp = (const float4*)(A.qws + base + qrow*32);
    #pragma unroll
    for (int i=0;i<8;i++){
      float4 q = qp[i];
      const float sc = 0.17677669529663687f;   // 1/sqrt(32) folded into q
      q.x*=sc; q.y*=sc; q.z*=sc; q.w*=sc;
      qv[i] = q;
      av[i] = float4{0.f,0.f,0.f,0.f};
    }
  }
  __syncthreads();

  float m = -1e30f, lsum = 0.f;
  #pragma unroll 2
  for (int j=0; j<193; ++j){
    const float4* kr = (const float4*)(Kl + j*32);
    // 4 independent partial dot chains for ILP
    float s0 = qv[0].x*kr[0].x + qv[0].y*kr[0].y + qv[0].z*kr[0].z + qv[0].w*kr[0].w;
    float s1 = qv[1].x*kr[1].x + qv[1].y*kr[1].y + qv[1].z*kr[1].z + qv[1].w*kr[1].w;
    float s2 = qv[2].x*kr[2].x + qv[2].y*kr[2].y + qv[2].z*kr[2].z + qv[2].w*kr[2].w;
    float s3 = qv[3].x*kr[3].x + qv[3].y*kr[3].y + qv[3].z*kr[3].z + qv[3].w*kr[3].w;
    s0 += qv[4].x*kr[4].x + qv[4].y*kr[4].y + qv[4].z*kr[4].z + qv[4].w*kr[4].w;
    s1 += qv[5].x*kr[5].x + qv[5].y*kr[5].y + qv[5].z*kr[5].z + qv[5].w*kr[5].w;
    s2 += qv[6].x*kr[6].x + qv[6].y*kr[6].y + qv[6].z*kr[6].z + qv[6].w*kr[6].w;
    s3 += qv[7].x*kr[7].x + qv[7].y*kr[7].y + qv[7].z*kr[7].z + qv[7].w*kr[7].w;
    float s = (s0+s1) + (s2+s3);
    if (s > m + 8.f){                      // rare rescale (defer-max, THR=8)
      float al = __expf(m - s);            // first iter: exp(-inf)=0 zeroes history
      lsum *= al;
      #pragma unroll
      for (int i=0;i<8;i++){ av[i].x*=al; av[i].y*=al; av[i].z*=al; av[i].w*=al; }
      m = s;
    }
    float p = __expf(s - m);               // bounded by e^8
    lsum += p;
    const float4* vr = (const float4*)(Vl + j*32);
    #pragma unroll
    for (int i=0;i<8;i++){
      av[i].x += p*vr[i].x; av[i].y += p*vr[i].y;
      av[i].z += p*vr[i].z; av[i].w += p*vr[i].w;
    }
  }

  if (t < 193){
    float inv = 1.f/lsum;
    size_t G = (size_t)b*193 + t;
    ushort_t* op = A.attws + G*64 + h*32;
    #pragma unroll
    for (int i=0;i<4;i++){
      ushortx8 u;
      float4 a0 = av[2*i], a1 = av[2*i+1];
      u[0]=f2b(a0.x*inv); u[1]=f2b(a0.y*inv); u[2]=f2b(a0.z*inv); u[3]=f2b(a0.w*inv);
      u[4]=f2b(a1.x*inv); u[5]=f2b(a1.y*inv); u[6]=f2b(a1.z*inv); u[7]=f2b(a1.w*inv);
      *(ushortx8*)(op + i*8) = u;
    }
  }
}

// ------------- fused: Z1=state+attn; Z2=LN(Z1); gelu(Z2@W1+b1)@W2+b2+Z1 -----
#define LZ1 68    // z1 f32 tile padded stride (272B, 16B-aligned)
#define LZ2 72    // z2 tile padded stride
#define LZ3 264   // z3 tile padded stride
__global__ __launch_bounds__(256) void k_ffn(Args A){
  const int mb = blockIdx.x, t = threadIdx.x, w = t>>6, l = t&63, lr = l&15, lq = l>>4;
  __shared__ __align__(16) float    z1t[64*LZ1];
  __shared__ __align__(16) ushort_t z2t[64*LZ2];
  __shared__ __align__(16) ushort_t z3t[64*LZ3];

  // prologue: z1 = state + attn (f32) into LDS
  {
    int row = t >> 2, seg = t & 3;
    const float* sp    = A.state + (size_t)(mb*64+row)*64 + seg*16;
    const ushort_t* ap = A.attws + (size_t)(mb*64+row)*64 + seg*16;
    float4 s0=((const float4*)sp)[0], s1=((const float4*)sp)[1],
           s2=((const float4*)sp)[2], s3=((const float4*)sp)[3];
    ushortx8 a0 = *(const ushortx8*)ap, a1 = *(const ushortx8*)(ap+8);
    float4 z0, z1, z2, z3;
    z0.x=s0.x+b2f(a0[0]); z0.y=s0.y+b2f(a0[1]); z0.z=s0.z+b2f(a0[2]); z0.w=s0.w+b2f(a0[3]);
    z1.x=s1.x+b2f(a0[4]); z1.y=s1.y+b2f(a0[5]); z1.z=s1.z+b2f(a0[6]); z1.w=s1.w+b2f(a0[7]);
    z2.x=s2.x+b2f(a1[0]); z2.y=s2.y+b2f(a1[1]); z2.z=s2.z+b2f(a1[2]); z2.w=s2.w+b2f(a1[3]);
    z3.x=s3.x+b2f(a1[4]); z3.y=s3.y+b2f(a1[5]); z3.z=s3.z+b2f(a1[6]); z3.w=s3.w+b2f(a1[7]);
    float* zp = z1t + row*LZ1 + seg*16;
    ((float4*)zp)[0]=z0; ((float4*)zp)[1]=z1; ((float4*)zp)[2]=z2; ((float4*)zp)[3]=z3;
  }
  __syncthreads();

  // LN(z1) -> z2t (bf16); 4 threads per row
  {
    int r = t >> 2, q4 = t & 3;
    float s=0.f, ss=0.f;
    #pragma unroll
    for (int c=0;c<16;c++){ float v = z1t[r*LZ1 + q4*16 + c]; s += v; ss += v*v; }
    s  += __shfl_xor(s,1);  s  += __shfl_xor(s,2);
    ss += __shfl_xor(ss,1); ss += __shfl_xor(ss,2);
    float mean = s*(1.f/64.f);
    float var  = fmaxf(ss*(1.f/64.f) - mean*mean, 0.f);
    float rstd = rsqrtf(var + 1e-5f);
    ushortx8 u0, u1;
    #pragma unroll
    for (int c=0;c<16;c++){
      int cc = q4*16 + c;
      float z2v = (z1t[r*LZ1 + cc]-mean)*rstd*A.g1[cc] + A.be1[cc];
      if (c < 8) u0[c] = f2b(z2v); else u1[c-8] = f2b(z2v);
    }
    ushort_t* zp = z2t + r*LZ2 + q4*16;
    *(ushortx8*)zp = u0;
    *(ushortx8*)(zp+8) = u1;
  }
  __syncthreads();

  // FFN1: 64x256, K=64. wave w covers cols 64w..64w+63 (4 16-col tiles)
  floatx4 acc[4][4];
  #pragma unroll
  for (int jj=0;jj<4;jj++)
    #pragma unroll
    for (int ra=0;ra<4;ra++) acc[jj][ra] = floatx4{0.f,0.f,0.f,0.f};
  #pragma unroll
  for (int kc=0;kc<2;kc++){
    short8 a[4], b[4];
    #pragma unroll
    for (int ra=0;ra<4;ra++) a[ra] = *(const short8*)(z2t + (16*ra+lr)*LZ2 + kc*32 + lq*8);
    #pragma unroll
    for (int jj=0;jj<4;jj++) b[jj] = *(const short8*)(A.w1T + (size_t)(64*w + 16*jj + lr)*64 + kc*32 + lq*8);
    #pragma unroll
    for (int jj=0;jj<4;jj++)
      #pragma unroll
      for (int ra=0;ra<4;ra++)
        acc[jj][ra] = __builtin_amdgcn_mfma_f32_16x16x32_bf16(a[ra], b[jj], acc[jj][ra], 0,0,0);
  }
  #pragma unroll
  for (int jj=0;jj<4;jj++){
    int col = 64*w + 16*jj + lr;
    float bb = A.bl1[col];
    #pragma unroll
    for (int ra=0;ra<4;ra++)
      #pragma unroll
      for (int r=0;r<4;r++){
        int row = 16*ra + lq*4 + r;
        float x = acc[jj][ra][r] + bb;
        float gl = 0.5f*x*(1.0f + erff(x*0.70710678118654752f));
        z3t[row*LZ3 + col] = f2b(gl);
      }
  }
  __syncthreads();

  // FFN2: 64x64, K=256. wave w covers cols 16w..16w+15
  floatx4 o[4];
  #pragma unroll
  for (int ra=0;ra<4;ra++) o[ra] = floatx4{0.f,0.f,0.f,0.f};
  #pragma unroll
  for (int kc=0;kc<8;kc++){
    short8 a[4];
    short8 b = *(const short8*)(A.w2T + (size_t)(16*w + lr)*256 + kc*32 + lq*8);
    #pragma unroll
    for (int ra=0;ra<4;ra++) a[ra] = *(const short8*)(z3t + (16*ra+lr)*LZ3 + kc*32 + lq*8);
    #pragma unroll
    for (int ra=0;ra<4;ra++)
      o[ra] = __builtin_amdgcn_mfma_f32_16x16x32_bf16(a[ra], b, o[ra], 0,0,0);
  }
  int col = 16*w + lr;
  float bb = A.bl2[col];
  #pragma unroll
  for (int ra=0;ra<4;ra++)
    #pragma unroll
    for (int r=0;r<4;r++){
      int row = 16*ra + lq*4 + r;
      size_t idx = (size_t)(mb*64+row)*64 + col;
      A.out[idx] = o[ra][r] + bb + z1t[row*LZ1 + col];  // residual from LDS
    }
}

extern "C" void kernel_launch(void* const* d_in, const int* in_sizes, int n_in,
                              void* d_out, int out_size, void* d_ws, size_t ws_size,
                              hipStream_t stream){
  (void)in_sizes; (void)n_in; (void)out_size; (void)ws_size;
  Args A;
  A.state = (const float*)d_in[0];
  A.C0=(const float*)d_in[1]; A.C1=(const float*)d_in[2]; A.C2=(const float*)d_in[3];
  A.C3=(const float*)d_in[4]; A.C4=(const float*)d_in[5]; A.C5=(const float*)d_in[6];
  A.Wq=(const float*)d_in[7];  A.Wk=(const float*)d_in[8];  A.Wv=(const float*)d_in[9];
  A.bq=(const float*)d_in[10]; A.bk=(const float*)d_in[11]; A.bv=(const float*)d_in[12];
  A.WCq=(const float*)d_in[13]; A.WCk=(const float*)d_in[14]; A.WCv=(const float*)d_in[15];
  A.bCq=(const float*)d_in[16]; A.bCk=(const float*)d_in[17]; A.bCv=(const float*)d_in[18];
  A.gQE=(const float*)d_in[19]; A.beQE=(const float*)d_in[20];
  A.gKE=(const float*)d_in[21]; A.beKE=(const float*)d_in[22];
  A.gVE=(const float*)d_in[23]; A.beVE=(const float*)d_in[24];
  A.gQH=(const float*)d_in[25]; A.beQH=(const float*)d_in[26];
  A.gKH=(const float*)d_in[27]; A.beKH=(const float*)d_in[28];
  A.gVH=(const float*)d_in[29]; A.beVH=(const float*)d_in[30];
  A.g1=(const float*)d_in[31]; A.be1=(const float*)d_in[32];
  A.W1=(const float*)d_in[33]; A.bl1=(const float*)d_in[34];
  A.W2=(const float*)d_in[35]; A.bl2=(const float*)d_in[36];

  // workspace layout (~45 MB)
  char* ws = (char*)d_ws;
  size_t off = 0;
  const size_t rowf = (size_t)NROW*64*sizeof(float);       // 12.65 MB
  const size_t rowh = (size_t)NROW*64*2;                   // 6.32 MB
  A.qws  = (float*)(ws+off); off += rowf;
  A.kws  = (float*)(ws+off); off += rowf;
  A.vws  = (float*)(ws+off); off += rowf;
  A.attws= (ushort_t*)(ws+off); off += rowh;
  A.weT  = (ushort_t*)(ws+off); off += 192*64*2;
  A.whT  = (ushort_t*)(ws+off); off += (size_t)192*1536*2;
  A.w1T  = (ushort_t*)(ws+off); off += 256*64*2;
  A.w2T  = (ushort_t*)(ws+off); off += 64*256*2;
  A.out  = (float*)d_out;

  k_prep <<<dim3(256),    dim3(256), 0, stream>>>(A);
  k_proj <<<dim3(MT),     dim3(256), 0, stream>>>(A);
  k_attn <<<dim3(256,2),  dim3(256), 0, stream>>>(A);
  k_ffn  <<<dim3(MT),     dim3(256), 0, stream>>>(A);
}